// Round 4
// baseline (949.909 us; speedup 1.0000x reference)
//
#include <hip/hip_runtime.h>

// x:    (2, 768, 8,8,8)   -> (2,768,512)
// out:  (2, 48, 64,64,64) -> (2,48,262144)
// output: (2, 32, 64,64,64)
constexpr int NCLS = 32;

// ws float offsets
constexpr int WS_POOL = 64;     // 2*768
constexpr int WS_XF  = 1600;    // 2*256
constexpr int WS_PAR = 2112;    // 2*32*153 = 9792
constexpr int WS_P2  = 11904;   // 768 blocks * {sum,sumsq}

__device__ __forceinline__ float wred(float v) {
#pragma unroll
  for (int off = 32; off > 0; off >>= 1) v += __shfl_down(v, off, 64);
  return v;
}

__device__ __forceinline__ float4 fma4(float w, float4 v, float4 a) {
  a.x = fmaf(w, v.x, a.x); a.y = fmaf(w, v.y, a.y);
  a.z = fmaf(w, v.z, a.z); a.w = fmaf(w, v.w, a.w);
  return a;
}
__device__ __forceinline__ float4 relu4(float4 a) {
  a.x = fmaxf(a.x, 0.f); a.y = fmaxf(a.y, 0.f);
  a.z = fmaxf(a.z, 0.f); a.w = fmaxf(a.w, 0.f);
  return a;
}
__device__ __forceinline__ float4 bcast4(float v) { return make_float4(v, v, v, v); }

// K1: 800 blocks. Blocks 0..767: GN2 partial sums (32768 contiguous floats each).
//     Blocks 768..799: GN1 stats + relu-mean pool for one (b,group) (24576 floats).
__global__ void k1_stats(const float* __restrict__ x, const float* __restrict__ oin,
                         const float* __restrict__ g1, const float* __restrict__ b1,
                         float* __restrict__ ws) {
  int t = threadIdx.x;
  int wid = t >> 6, lane = t & 63;
  __shared__ float red[8];
  if (blockIdx.x < 768) {
    int blk = blockIdx.x;
    const float4* p = reinterpret_cast<const float4*>(oin + (size_t)blk * 32768);
    float s = 0.f, s2 = 0.f;
#pragma unroll
    for (int k = 0; k < 32; ++k) {
      float4 v = p[k * 256 + t];
      s  += v.x + v.y + v.z + v.w;
      s2 += v.x*v.x + v.y*v.y + v.z*v.z + v.w*v.w;
    }
    s = wred(s); s2 = wred(s2);
    if (lane == 0) { red[wid*2] = s; red[wid*2+1] = s2; }
    __syncthreads();
    if (t == 0) {
      ws[WS_P2 + blk*2]   = red[0]+red[2]+red[4]+red[6];
      ws[WS_P2 + blk*2+1] = red[1]+red[3]+red[5]+red[7];
    }
  } else {
    int g = blockIdx.x - 768;              // b = g>>4, grp = g&15
    __shared__ float mstat[2];
    const float4* p = reinterpret_cast<const float4*>(x + g * 24576);
    float s = 0.f, s2 = 0.f;
#pragma unroll
    for (int k = 0; k < 24; ++k) {
      float4 v = p[k * 256 + t];
      s  += v.x + v.y + v.z + v.w;
      s2 += v.x*v.x + v.y*v.y + v.z*v.z + v.w*v.w;
    }
    s = wred(s); s2 = wred(s2);
    if (lane == 0) { red[wid*2] = s; red[wid*2+1] = s2; }
    __syncthreads();
    if (t == 0) {
      float S  = red[0]+red[2]+red[4]+red[6];
      float S2 = red[1]+red[3]+red[5]+red[7];
      float mean = S * (1.f/24576.f);
      float var  = S2 * (1.f/24576.f) - mean*mean;
      mstat[0] = mean; mstat[1] = rsqrtf(var + 1e-5f);
    }
    __syncthreads();
    float mean = mstat[0], rstd = mstat[1];
#pragma unroll
    for (int k = 0; k < 12; ++k) {
      int i = k*4 + wid;                   // channel within group [0,48)
      int c = (g & 15) * 48 + i;           // channel [0,768)
      float sc = rstd * g1[c];
      float sh = b1[c] - mean * sc;
      const float* q = x + g * 24576 + i * 512;
      float acc = 0.f;
#pragma unroll
      for (int j = 0; j < 8; ++j)
        acc += fmaxf(fmaf(q[lane + j*64], sc, sh), 0.f);
      acc = wred(acc);
      if (lane == 0) ws[WS_POOL + (g >> 4) * 768 + c] = acc * (1.f/512.f);
    }
  }
}

// K2: x_feat, wave-per-output (coalesced row reads). 512 outputs -> 128 blocks.
__global__ void k2_xfeat(const float* __restrict__ gapw, const float* __restrict__ gapb,
                         float* __restrict__ ws) {
  int wid = threadIdx.x >> 6, lane = threadIdx.x & 63;
  int idx = blockIdx.x * 4 + wid;          // [0,512)
  int b = idx >> 8, o = idx & 255;
  const float* pw = gapw + o * 768;
  const float* pp = ws + WS_POOL + b * 768;
  float s = 0.f;
#pragma unroll
  for (int i = 0; i < 12; ++i) {
    int cc = lane + i*64;
    s += pw[cc] * pp[cc];
  }
  s = wred(s);
  if (lane == 0) ws[WS_XF + idx] = s + gapb[o];
}

// K3: params, wave-per-output (coalesced). 9792 outputs -> 2448 blocks.
__global__ void k3_params(const float* __restrict__ cw, const float* __restrict__ cb,
                          const float* __restrict__ te, float* __restrict__ ws) {
  int wid = threadIdx.x >> 6, lane = threadIdx.x & 63;
  int e = blockIdx.x * 4 + wid;            // [0,9792)
  int b = e / (NCLS * 153);
  int r = e % (NCLS * 153);
  int c = r / 153, p = r % 153;
  const float* w  = cw + p * 512;
  const float* xf = ws + WS_XF + b * 256;
  const float* tv = te + c * 256;
  float s = 0.f;
#pragma unroll
  for (int i = 0; i < 4; ++i) {
    int f = lane + i*64;
    s += w[f] * xf[f] + w[256 + f] * tv[f];
  }
  s = wred(s);
  if (lane == 0) ws[WS_PAR + e] = s + cb[p];
}

// K4: fused GN2-finalize + main head.
// 1024 blocks x 256 thr. Block tile = 512 voxels (128 float4-quads); each thread
// handles 8 voxels (quads lane and lane+64). The block's 4 waves redundantly
// compute h0 for the SAME voxels, then each wave runs 8 of the 32 classes.
// -> 4096 waves total (4 blocks/CU issueable), LDS W-reads amortized over 8 voxels.
__global__ __launch_bounds__(256, 3) void k4_main(const float* __restrict__ oin,
                                                  const float* __restrict__ prew,
                                                  const float* __restrict__ preb,
                                                  const float* __restrict__ g2,
                                                  const float* __restrict__ b2,
                                                  const float* __restrict__ ws,
                                                  float* __restrict__ out) {
  __shared__ __align__(16) float Wl[NCLS * 160];
  __shared__ __align__(16) float prewT[384];
  __shared__ float2 ssl[48];
  __shared__ float ms[64];
  int t = threadIdx.x;
  int w = t >> 6, lane = t & 63;
  int b = blockIdx.x >> 9, tile = blockIdx.x & 511;

  if (t < 32) {
    float S = 0.f, S2 = 0.f;
#pragma unroll
    for (int k = 0; k < 24; ++k) {
      S  += ws[WS_P2 + (t*24 + k)*2];
      S2 += ws[WS_P2 + (t*24 + k)*2 + 1];
    }
    float mean = S * (1.f/786432.f);
    float var  = S2 * (1.f/786432.f) - mean*mean;
    ms[t*2] = mean; ms[t*2+1] = rsqrtf(var + 1e-5f);
  }
  if (t < 128) {
#pragma unroll
    for (int k = 0; k < 3; ++k) {
      int i = t + k*128;
      prewT[(i % 48) * 8 + (i / 48)] = prew[i];
    }
  }
  {
    const float* wsrc = ws + WS_PAR + b * (NCLS*153);
#pragma unroll 4
    for (int cc = 0; cc < NCLS; ++cc)
      if (t < 153) Wl[cc*160 + t] = wsrc[cc*153 + t];
  }
  __syncthreads();
  if (t < 48) {
    int grp = (b << 4) + t / 3;
    float mean = ms[grp*2], rstd = ms[grp*2+1];
    float sc = rstd * g2[t];
    ssl[t] = make_float2(sc, b2[t] - mean * sc);
  }
  __syncthreads();

  // h0 for this thread's 8 voxels (quads: lane and lane+64 within the tile)
  const float4* ip4 = reinterpret_cast<const float4*>(oin)
                      + (size_t)b * 48 * 65536 + tile*128 + lane;
  const float4* pT4 = reinterpret_cast<const float4*>(prewT);
  float4 h0a[8], h0b[8];
#pragma unroll
  for (int o = 0; o < 8; ++o) { float pb = preb[o]; h0a[o] = bcast4(pb); h0b[o] = bcast4(pb); }
#pragma unroll
  for (int c = 0; c < 48; ++c) {
    float4 va = ip4[(size_t)c * 65536];
    float4 vb = ip4[(size_t)c * 65536 + 64];
    float2 ss = ssl[c];
    float4 ga = relu4(make_float4(fmaf(va.x, ss.x, ss.y), fmaf(va.y, ss.x, ss.y),
                                  fmaf(va.z, ss.x, ss.y), fmaf(va.w, ss.x, ss.y)));
    float4 gb = relu4(make_float4(fmaf(vb.x, ss.x, ss.y), fmaf(vb.y, ss.x, ss.y),
                                  fmaf(vb.z, ss.x, ss.y), fmaf(vb.w, ss.x, ss.y)));
    float4 w0 = pT4[c*2], w1 = pT4[c*2+1];
    h0a[0] = fma4(w0.x, ga, h0a[0]); h0b[0] = fma4(w0.x, gb, h0b[0]);
    h0a[1] = fma4(w0.y, ga, h0a[1]); h0b[1] = fma4(w0.y, gb, h0b[1]);
    h0a[2] = fma4(w0.z, ga, h0a[2]); h0b[2] = fma4(w0.z, gb, h0b[2]);
    h0a[3] = fma4(w0.w, ga, h0a[3]); h0b[3] = fma4(w0.w, gb, h0b[3]);
    h0a[4] = fma4(w1.x, ga, h0a[4]); h0b[4] = fma4(w1.x, gb, h0b[4]);
    h0a[5] = fma4(w1.y, ga, h0a[5]); h0b[5] = fma4(w1.y, gb, h0b[5]);
    h0a[6] = fma4(w1.z, ga, h0a[6]); h0b[6] = fma4(w1.z, gb, h0b[6]);
    h0a[7] = fma4(w1.w, ga, h0a[7]); h0b[7] = fma4(w1.w, gb, h0b[7]);
  }

  float4* op4 = reinterpret_cast<float4*>(out)
                + (size_t)b * NCLS * 65536 + tile*128 + lane;
#pragma unroll 1
  for (int k = 0; k < 8; ++k) {
    int cls = (w << 3) | k;                // this wave's 8 classes
    const float4* W4 = reinterpret_cast<const float4*>(Wl + cls * 160);
    float4 b1q0 = W4[34], b1q1 = W4[35];   // b1[0..7]
    float4 b2q0 = W4[36], b2q1 = W4[37];   // b2[0..7]
    float4 w3q0 = W4[32], w3q1 = W4[33];   // w3[0..7]
    float b3v = W4[38].x;
    float b1arr[8] = {b1q0.x,b1q0.y,b1q0.z,b1q0.w,b1q1.x,b1q1.y,b1q1.z,b1q1.w};
    float b2arr[8] = {b2q0.x,b2q0.y,b2q0.z,b2q0.w,b2q1.x,b2q1.y,b2q1.z,b2q1.w};
    float w3arr[8] = {w3q0.x,w3q0.y,w3q0.z,w3q0.w,w3q1.x,w3q1.y,w3q1.z,w3q1.w};

    float4 t1a[8], t1b[8];
#pragma unroll
    for (int i = 0; i < 8; ++i) {
      float4 w0 = W4[i*2], w1 = W4[i*2+1];
      float4 aA = bcast4(b1arr[i]), aB = bcast4(b1arr[i]);
      aA = fma4(w0.x, h0a[0], aA); aB = fma4(w0.x, h0b[0], aB);
      aA = fma4(w0.y, h0a[1], aA); aB = fma4(w0.y, h0b[1], aB);
      aA = fma4(w0.z, h0a[2], aA); aB = fma4(w0.z, h0b[2], aB);
      aA = fma4(w0.w, h0a[3], aA); aB = fma4(w0.w, h0b[3], aB);
      aA = fma4(w1.x, h0a[4], aA); aB = fma4(w1.x, h0b[4], aB);
      aA = fma4(w1.y, h0a[5], aA); aB = fma4(w1.y, h0b[5], aB);
      aA = fma4(w1.z, h0a[6], aA); aB = fma4(w1.z, h0b[6], aB);
      aA = fma4(w1.w, h0a[7], aA); aB = fma4(w1.w, h0b[7], aB);
      t1a[i] = relu4(aA); t1b[i] = relu4(aB);
    }
    // layer2 + layer3 fused (t2 row consumed immediately)
    float4 lgA = bcast4(b3v), lgB = bcast4(b3v);
#pragma unroll
    for (int i = 0; i < 8; ++i) {
      float4 w0 = W4[16 + i*2], w1 = W4[17 + i*2];
      float4 aA = bcast4(b2arr[i]), aB = bcast4(b2arr[i]);
      aA = fma4(w0.x, t1a[0], aA); aB = fma4(w0.x, t1b[0], aB);
      aA = fma4(w0.y, t1a[1], aA); aB = fma4(w0.y, t1b[1], aB);
      aA = fma4(w0.z, t1a[2], aA); aB = fma4(w0.z, t1b[2], aB);
      aA = fma4(w0.w, t1a[3], aA); aB = fma4(w0.w, t1b[3], aB);
      aA = fma4(w1.x, t1a[4], aA); aB = fma4(w1.x, t1b[4], aB);
      aA = fma4(w1.y, t1a[5], aA); aB = fma4(w1.y, t1b[5], aB);
      aA = fma4(w1.z, t1a[6], aA); aB = fma4(w1.z, t1b[6], aB);
      aA = fma4(w1.w, t1a[7], aA); aB = fma4(w1.w, t1b[7], aB);
      aA = relu4(aA); aB = relu4(aB);
      lgA = fma4(w3arr[i], aA, lgA); lgB = fma4(w3arr[i], aB, lgB);
    }
    op4[(size_t)cls * 65536]      = lgA;
    op4[(size_t)cls * 65536 + 64] = lgB;
  }
}

extern "C" void kernel_launch(void* const* d_in, const int* in_sizes, int n_in,
                              void* d_out, int out_size, void* d_ws, size_t ws_size,
                              hipStream_t stream) {
  const float* x    = (const float*)d_in[0];
  const float* oin  = (const float*)d_in[1];
  const float* te   = (const float*)d_in[2];
  const float* g1   = (const float*)d_in[3];
  const float* b1   = (const float*)d_in[4];
  const float* gapw = (const float*)d_in[5];
  const float* gapb = (const float*)d_in[6];
  const float* cw   = (const float*)d_in[7];
  const float* cb   = (const float*)d_in[8];
  const float* g2   = (const float*)d_in[9];
  const float* b2   = (const float*)d_in[10];
  const float* prew = (const float*)d_in[11];
  const float* preb = (const float*)d_in[12];
  float* ws  = (float*)d_ws;
  float* out = (float*)d_out;

  hipLaunchKernelGGL(k1_stats,  dim3(800),  dim3(256), 0, stream, x, oin, g1, b1, ws);
  hipLaunchKernelGGL(k2_xfeat,  dim3(128),  dim3(256), 0, stream, gapw, gapb, ws);
  hipLaunchKernelGGL(k3_params, dim3(2448), dim3(256), 0, stream, cw, cb, te, ws);
  hipLaunchKernelGGL(k4_main,   dim3(1024), dim3(256), 0, stream, oin, prew, preb, g2, b2, ws, out);
}

// Round 5
// 398.540 us; speedup vs baseline: 2.3835x; 2.3835x over previous
//
#include <hip/hip_runtime.h>

// x:    (2, 768, 8,8,8)   -> (2,768,512)
// out:  (2, 48, 64,64,64) -> (2,48,262144)
// output: (2, 32, 64,64,64)
constexpr int NCLS = 32;

// ws float offsets
constexpr int WS_POOL = 64;     // 2*768
constexpr int WS_XF  = 1600;    // 2*256
constexpr int WS_PAR = 2112;    // 2*32*153 = 9792
constexpr int WS_P2  = 11904;   // 768 blocks * {sum,sumsq}

__device__ __forceinline__ float wred(float v) {
#pragma unroll
  for (int off = 32; off > 0; off >>= 1) v += __shfl_down(v, off, 64);
  return v;
}

__device__ __forceinline__ float4 fma4(float w, float4 v, float4 a) {
  a.x = fmaf(w, v.x, a.x); a.y = fmaf(w, v.y, a.y);
  a.z = fmaf(w, v.z, a.z); a.w = fmaf(w, v.w, a.w);
  return a;
}
__device__ __forceinline__ float4 relu4(float4 a) {
  a.x = fmaxf(a.x, 0.f); a.y = fmaxf(a.y, 0.f);
  a.z = fmaxf(a.z, 0.f); a.w = fmaxf(a.w, 0.f);
  return a;
}
__device__ __forceinline__ float4 bcast4(float v) { return make_float4(v, v, v, v); }

// K1: 800 blocks. Blocks 0..767: GN2 partial sums (32768 contiguous floats each).
//     Blocks 768..799: GN1 stats + relu-mean pool for one (b,group) (24576 floats).
__global__ void k1_stats(const float* __restrict__ x, const float* __restrict__ oin,
                         const float* __restrict__ g1, const float* __restrict__ b1,
                         float* __restrict__ ws) {
  int t = threadIdx.x;
  int wid = t >> 6, lane = t & 63;
  __shared__ float red[8];
  if (blockIdx.x < 768) {
    int blk = blockIdx.x;
    const float4* p = reinterpret_cast<const float4*>(oin + (size_t)blk * 32768);
    float s = 0.f, s2 = 0.f;
#pragma unroll
    for (int k = 0; k < 32; ++k) {
      float4 v = p[k * 256 + t];
      s  += v.x + v.y + v.z + v.w;
      s2 += v.x*v.x + v.y*v.y + v.z*v.z + v.w*v.w;
    }
    s = wred(s); s2 = wred(s2);
    if (lane == 0) { red[wid*2] = s; red[wid*2+1] = s2; }
    __syncthreads();
    if (t == 0) {
      ws[WS_P2 + blk*2]   = red[0]+red[2]+red[4]+red[6];
      ws[WS_P2 + blk*2+1] = red[1]+red[3]+red[5]+red[7];
    }
  } else {
    int g = blockIdx.x - 768;              // b = g>>4, grp = g&15
    __shared__ float mstat[2];
    const float4* p = reinterpret_cast<const float4*>(x + g * 24576);
    float s = 0.f, s2 = 0.f;
#pragma unroll
    for (int k = 0; k < 24; ++k) {
      float4 v = p[k * 256 + t];
      s  += v.x + v.y + v.z + v.w;
      s2 += v.x*v.x + v.y*v.y + v.z*v.z + v.w*v.w;
    }
    s = wred(s); s2 = wred(s2);
    if (lane == 0) { red[wid*2] = s; red[wid*2+1] = s2; }
    __syncthreads();
    if (t == 0) {
      float S  = red[0]+red[2]+red[4]+red[6];
      float S2 = red[1]+red[3]+red[5]+red[7];
      float mean = S * (1.f/24576.f);
      float var  = S2 * (1.f/24576.f) - mean*mean;
      mstat[0] = mean; mstat[1] = rsqrtf(var + 1e-5f);
    }
    __syncthreads();
    float mean = mstat[0], rstd = mstat[1];
#pragma unroll
    for (int k = 0; k < 12; ++k) {
      int i = k*4 + wid;                   // channel within group [0,48)
      int c = (g & 15) * 48 + i;           // channel [0,768)
      float sc = rstd * g1[c];
      float sh = b1[c] - mean * sc;
      const float* q = x + g * 24576 + i * 512;
      float acc = 0.f;
#pragma unroll
      for (int j = 0; j < 8; ++j)
        acc += fmaxf(fmaf(q[lane + j*64], sc, sh), 0.f);
      acc = wred(acc);
      if (lane == 0) ws[WS_POOL + (g >> 4) * 768 + c] = acc * (1.f/512.f);
    }
  }
}

// K2: x_feat, wave-per-output (coalesced row reads). 512 outputs -> 128 blocks.
__global__ void k2_xfeat(const float* __restrict__ gapw, const float* __restrict__ gapb,
                         float* __restrict__ ws) {
  int wid = threadIdx.x >> 6, lane = threadIdx.x & 63;
  int idx = blockIdx.x * 4 + wid;          // [0,512)
  int b = idx >> 8, o = idx & 255;
  const float* pw = gapw + o * 768;
  const float* pp = ws + WS_POOL + b * 768;
  float s = 0.f;
#pragma unroll
  for (int i = 0; i < 12; ++i) {
    int cc = lane + i*64;
    s += pw[cc] * pp[cc];
  }
  s = wred(s);
  if (lane == 0) ws[WS_XF + idx] = s + gapb[o];
}

// K3: params, wave-per-output (coalesced). 9792 outputs -> 2448 blocks.
__global__ void k3_params(const float* __restrict__ cw, const float* __restrict__ cb,
                          const float* __restrict__ te, float* __restrict__ ws) {
  int wid = threadIdx.x >> 6, lane = threadIdx.x & 63;
  int e = blockIdx.x * 4 + wid;            // [0,9792)
  int b = e / (NCLS * 153);
  int r = e % (NCLS * 153);
  int c = r / 153, p = r % 153;
  const float* w  = cw + p * 512;
  const float* xf = ws + WS_XF + b * 256;
  const float* tv = te + c * 256;
  float s = 0.f;
#pragma unroll
  for (int i = 0; i < 4; ++i) {
    int f = lane + i*64;
    s += w[f] * xf[f] + w[256 + f] * tv[f];
  }
  s = wred(s);
  if (lane == 0) ws[WS_PAR + e] = s + cb[p];
}

// K4: fused GN2-finalize + main head.
// 1024 blocks x 256 thr. Block tile = 512 voxels; thread = 8 voxels (quads lane, lane+64).
// The block's 4 waves redundantly compute h0 for the SAME voxels; each wave then runs
// 8 of the 32 classes -> 4096 waves. launch_bounds(256,2): VGPR cap 256 (no spills!),
// 2 blocks/CU resident. (256,3) capped VGPR at ~170-, spilled h0/t1 to scratch -> 2.3 GB
// of HBM scratch traffic, 800 us. Never cap below ~230 here.
__global__ __launch_bounds__(256, 2) void k4_main(const float* __restrict__ oin,
                                                  const float* __restrict__ prew,
                                                  const float* __restrict__ preb,
                                                  const float* __restrict__ g2,
                                                  const float* __restrict__ b2,
                                                  const float* __restrict__ ws,
                                                  float* __restrict__ out) {
  __shared__ __align__(16) float Wl[NCLS * 160];
  __shared__ __align__(16) float prewT[384];
  __shared__ float2 ssl[48];
  __shared__ float ms[64];
  int t = threadIdx.x;
  int w = t >> 6, lane = t & 63;
  int b = blockIdx.x >> 9, tile = blockIdx.x & 511;

  if (t < 32) {
    float S = 0.f, S2 = 0.f;
#pragma unroll
    for (int k = 0; k < 24; ++k) {
      S  += ws[WS_P2 + (t*24 + k)*2];
      S2 += ws[WS_P2 + (t*24 + k)*2 + 1];
    }
    float mean = S * (1.f/786432.f);
    float var  = S2 * (1.f/786432.f) - mean*mean;
    ms[t*2] = mean; ms[t*2+1] = rsqrtf(var + 1e-5f);
  }
  if (t < 128) {
#pragma unroll
    for (int k = 0; k < 3; ++k) {
      int i = t + k*128;
      prewT[(i % 48) * 8 + (i / 48)] = prew[i];
    }
  }
  {
    const float* wsrc = ws + WS_PAR + b * (NCLS*153);
#pragma unroll 4
    for (int cc = 0; cc < NCLS; ++cc)
      if (t < 153) Wl[cc*160 + t] = wsrc[cc*153 + t];
  }
  __syncthreads();
  if (t < 48) {
    int grp = (b << 4) + t / 3;
    float mean = ms[grp*2], rstd = ms[grp*2+1];
    float sc = rstd * g2[t];
    ssl[t] = make_float2(sc, b2[t] - mean * sc);
  }
  __syncthreads();

  // h0 for this thread's 8 voxels (quads: lane and lane+64 within the tile)
  const float4* ip4 = reinterpret_cast<const float4*>(oin)
                      + (size_t)b * 48 * 65536 + tile*128 + lane;
  const float4* pT4 = reinterpret_cast<const float4*>(prewT);
  float4 h0a[8], h0b[8];
#pragma unroll
  for (int o = 0; o < 8; ++o) { float pb = preb[o]; h0a[o] = bcast4(pb); h0b[o] = bcast4(pb); }
#pragma unroll
  for (int c = 0; c < 48; ++c) {
    float4 va = ip4[(size_t)c * 65536];
    float4 vb = ip4[(size_t)c * 65536 + 64];
    float2 ss = ssl[c];
    float4 ga = relu4(make_float4(fmaf(va.x, ss.x, ss.y), fmaf(va.y, ss.x, ss.y),
                                  fmaf(va.z, ss.x, ss.y), fmaf(va.w, ss.x, ss.y)));
    float4 gb = relu4(make_float4(fmaf(vb.x, ss.x, ss.y), fmaf(vb.y, ss.x, ss.y),
                                  fmaf(vb.z, ss.x, ss.y), fmaf(vb.w, ss.x, ss.y)));
    float4 w0 = pT4[c*2], w1 = pT4[c*2+1];
    h0a[0] = fma4(w0.x, ga, h0a[0]); h0b[0] = fma4(w0.x, gb, h0b[0]);
    h0a[1] = fma4(w0.y, ga, h0a[1]); h0b[1] = fma4(w0.y, gb, h0b[1]);
    h0a[2] = fma4(w0.z, ga, h0a[2]); h0b[2] = fma4(w0.z, gb, h0b[2]);
    h0a[3] = fma4(w0.w, ga, h0a[3]); h0b[3] = fma4(w0.w, gb, h0b[3]);
    h0a[4] = fma4(w1.x, ga, h0a[4]); h0b[4] = fma4(w1.x, gb, h0b[4]);
    h0a[5] = fma4(w1.y, ga, h0a[5]); h0b[5] = fma4(w1.y, gb, h0b[5]);
    h0a[6] = fma4(w1.z, ga, h0a[6]); h0b[6] = fma4(w1.z, gb, h0b[6]);
    h0a[7] = fma4(w1.w, ga, h0a[7]); h0b[7] = fma4(w1.w, gb, h0b[7]);
  }

  float4* op4 = reinterpret_cast<float4*>(out)
                + (size_t)b * NCLS * 65536 + tile*128 + lane;
#pragma unroll 1
  for (int k = 0; k < 8; ++k) {
    int cls = (w << 3) | k;                // this wave's 8 classes
    const float4* W4 = reinterpret_cast<const float4*>(Wl + cls * 160);
    float4 b1q0 = W4[34], b1q1 = W4[35];   // b1[0..7]
    float4 b2q0 = W4[36], b2q1 = W4[37];   // b2[0..7]
    float4 w3q0 = W4[32], w3q1 = W4[33];   // w3[0..7]
    float b3v = W4[38].x;
    float b1arr[8] = {b1q0.x,b1q0.y,b1q0.z,b1q0.w,b1q1.x,b1q1.y,b1q1.z,b1q1.w};
    float b2arr[8] = {b2q0.x,b2q0.y,b2q0.z,b2q0.w,b2q1.x,b2q1.y,b2q1.z,b2q1.w};
    float w3arr[8] = {w3q0.x,w3q0.y,w3q0.z,w3q0.w,w3q1.x,w3q1.y,w3q1.z,w3q1.w};

    float4 t1a[8], t1b[8];
#pragma unroll
    for (int i = 0; i < 8; ++i) {
      float4 w0 = W4[i*2], w1 = W4[i*2+1];
      float4 aA = bcast4(b1arr[i]), aB = bcast4(b1arr[i]);
      aA = fma4(w0.x, h0a[0], aA); aB = fma4(w0.x, h0b[0], aB);
      aA = fma4(w0.y, h0a[1], aA); aB = fma4(w0.y, h0b[1], aB);
      aA = fma4(w0.z, h0a[2], aA); aB = fma4(w0.z, h0b[2], aB);
      aA = fma4(w0.w, h0a[3], aA); aB = fma4(w0.w, h0b[3], aB);
      aA = fma4(w1.x, h0a[4], aA); aB = fma4(w1.x, h0b[4], aB);
      aA = fma4(w1.y, h0a[5], aA); aB = fma4(w1.y, h0b[5], aB);
      aA = fma4(w1.z, h0a[6], aA); aB = fma4(w1.z, h0b[6], aB);
      aA = fma4(w1.w, h0a[7], aA); aB = fma4(w1.w, h0b[7], aB);
      t1a[i] = relu4(aA); t1b[i] = relu4(aB);
    }
    // layer2 + layer3 fused (t2 row consumed immediately)
    float4 lgA = bcast4(b3v), lgB = bcast4(b3v);
#pragma unroll
    for (int i = 0; i < 8; ++i) {
      float4 w0 = W4[16 + i*2], w1 = W4[17 + i*2];
      float4 aA = bcast4(b2arr[i]), aB = bcast4(b2arr[i]);
      aA = fma4(w0.x, t1a[0], aA); aB = fma4(w0.x, t1b[0], aB);
      aA = fma4(w0.y, t1a[1], aA); aB = fma4(w0.y, t1b[1], aB);
      aA = fma4(w0.z, t1a[2], aA); aB = fma4(w0.z, t1b[2], aB);
      aA = fma4(w0.w, t1a[3], aA); aB = fma4(w0.w, t1b[3], aB);
      aA = fma4(w1.x, t1a[4], aA); aB = fma4(w1.x, t1b[4], aB);
      aA = fma4(w1.y, t1a[5], aA); aB = fma4(w1.y, t1b[5], aB);
      aA = fma4(w1.z, t1a[6], aA); aB = fma4(w1.z, t1b[6], aB);
      aA = fma4(w1.w, t1a[7], aA); aB = fma4(w1.w, t1b[7], aB);
      aA = relu4(aA); aB = relu4(aB);
      lgA = fma4(w3arr[i], aA, lgA); lgB = fma4(w3arr[i], aB, lgB);
    }
    op4[(size_t)cls * 65536]      = lgA;
    op4[(size_t)cls * 65536 + 64] = lgB;
  }
}

extern "C" void kernel_launch(void* const* d_in, const int* in_sizes, int n_in,
                              void* d_out, int out_size, void* d_ws, size_t ws_size,
                              hipStream_t stream) {
  const float* x    = (const float*)d_in[0];
  const float* oin  = (const float*)d_in[1];
  const float* te   = (const float*)d_in[2];
  const float* g1   = (const float*)d_in[3];
  const float* b1   = (const float*)d_in[4];
  const float* gapw = (const float*)d_in[5];
  const float* gapb = (const float*)d_in[6];
  const float* cw   = (const float*)d_in[7];
  const float* cb   = (const float*)d_in[8];
  const float* g2   = (const float*)d_in[9];
  const float* b2   = (const float*)d_in[10];
  const float* prew = (const float*)d_in[11];
  const float* preb = (const float*)d_in[12];
  float* ws  = (float*)d_ws;
  float* out = (float*)d_out;

  hipLaunchKernelGGL(k1_stats,  dim3(800),  dim3(256), 0, stream, x, oin, g1, b1, ws);
  hipLaunchKernelGGL(k2_xfeat,  dim3(128),  dim3(256), 0, stream, gapw, gapb, ws);
  hipLaunchKernelGGL(k3_params, dim3(2448), dim3(256), 0, stream, cw, cb, te, ws);
  hipLaunchKernelGGL(k4_main,   dim3(1024), dim3(256), 0, stream, oin, prew, preb, g2, b2, ws, out);
}